// Round 7
// baseline (420.240 us; speedup 1.0000x reference)
//
#include <hip/hip_runtime.h>

#define BLK 256

constexpr int Bn = 4, Cn = 3, Hn = 1024, Wn = 1024;
constexpr int HW   = Hn * Wn;        // 1<<20
constexpr int BHW  = Bn * HW;        // 4,194,304
constexpr int BCHW = Bn * Cn * HW;   // 12,582,912
constexpr int MAX_ITERS = 4;

// dest-tile ownership splat
constexpr int TS  = 64;              // dest tile side
constexpr int Mg  = 24;              // source window margin
constexpr int WND = TS + 2 * Mg;     // 112
constexpr int NW  = WND * WND;       // 12544
constexpr float FMAX = 23.0f;        // = Mg-1; owner handles |f|<=FMAX exactly

// packed-u64 fixed point (R6: DS instruction count is the invariant bottleneck;
// 2x ds_add_u64 replaces 3x ds_add_u32 + flag write).
//   word1: hi = c1*2^13 (mod 2^32 exact), lo = c0*2^13 + 2^19 (>=0, carry-free:
//          worst-case 2304 events/cell * 2^20 < 2^32)
//   word2: hi = c2*2^13, lo = +1/event (count N; N>0 == hole flag, free)
constexpr float SCALE = 8192.0f;                 // 2^13
constexpr float INVSC = 1.220703125e-04f;        // 2^-13 exact
constexpr unsigned BIAS_I = 524288u;             // 64*SCALE = 2^19

constexpr int FB_CAP = 1 << 19;      // fallback list capacity (16x margin)

// flow-only prefetch; sentinel 1e9 fails the FMAX test for out-of-image px
#define STAGEF(PRED, WY, WX, F, PX, PY)                                       \
    {   PY = ty - Mg + (WY);                                                  \
        PX = tx - Mg + (WX);                                                  \
        F = make_float2(1e9f, 1e9f);                                          \
        if ((PRED) && (unsigned)PY < (unsigned)Hn &&                          \
            (unsigned)PX < (unsigned)Wn)                                      \
            F = flb[(PY << 10) + PX];                                         \
    }

__global__ __launch_bounds__(1024, 8) void splat_owner(
    const float* __restrict__ im0, const float* __restrict__ flow,
    float* __restrict__ acc, unsigned* __restrict__ wm,
    unsigned* __restrict__ fb_count, unsigned* __restrict__ fb_list)
{
    __shared__ unsigned long long s_w1[TS * TS];  // [c1 | c0+bias] : 32 KiB
    __shared__ unsigned long long s_w2[TS * TS];  // [c2 | count  ] : 32 KiB
    // XCD-bijective swizzle (1024 blocks, 8 XCDs): contiguous tile rows/XCD
    const int bid  = ((blockIdx.x & 7) << 7) | (blockIdx.x >> 3);
    const int b    = bid >> 8;        // 256 tiles per batch (16x16)
    const int tile = bid & 255;
    const int ty   = (tile >> 4) * TS;
    const int tx   = (tile & 15) * TS;

    for (int i = threadIdx.x; i < TS * TS; i += 1024) {
        s_w1[i] = 0ull; s_w2[i] = 0ull;
    }
    __syncthreads();

    const float*  imb = im0 + (size_t)b * Cn * HW;
    const float2* flb = reinterpret_cast<const float2*>(flow) + (size_t)b * HW;

    int i  = threadIdx.x;
    int wy = i / WND, wx = i - wy * WND;      // one-time div (i < 1024)
    int axp, ayp; float2 fA;
    STAGEF(true, wy, wx, fA, axp, ayp);

    while (i < NW) {
        int ni  = i + 1024;
        int nwx = wx + (1024 % WND);          // +16
        int nwy = wy + (1024 / WND);          // +9
        if (nwx >= WND) { nwx -= WND; ++nwy; }
        // prefetch next visit's flow before processing this one
        int bxp, byp; float2 fB;
        STAGEF(ni < NW, nwy, nwx, fB, bxp, byp);

        bool small_f = (fabsf(fA.x) <= FMAX && fabsf(fA.y) <= FMAX);

        // fallback detection: each image px is in exactly one tile's core;
        // its owner appends it to the compact list (compiler wave-aggregates
        // the atomic). ~33K appends total across the whole grid.
        bool in_core = (wy >= Mg && wy < Mg + TS && wx >= Mg && wx < Mg + TS);
        if (__any(in_core && !small_f)) {
            if (in_core && !small_f) {
                unsigned slot = atomicAdd(fb_count, 1u);
                if (slot < (unsigned)FB_CAP)
                    fb_list[slot] = (unsigned)(b * HW + (ayp << 10) + axp);
            }
        }

        if (small_f) {
            float X = (float)axp + fA.x;
            float Y = (float)ayp + fA.y;
            float x0 = floorf(X), y0 = floorf(Y);
            int lx0 = (int)x0 - tx;
            int ly0 = (int)y0 - ty;
            // box reject: any of the 2x2 corners inside this tile?
            if (lx0 >= -1 && lx0 < TS && ly0 >= -1 && ly0 < TS) {
                // shared bilinear factors; per-corner product identical to ref
                float wxa = 1.f - fabsf(X - x0);
                float wxb = 1.f - fabsf(X - (x0 + 1.f));
                float wya = 1.f - fabsf(Y - y0);
                float wyb = 1.f - fabsf(Y - (y0 + 1.f));
                float w00 = wxa * wya, w01 = wxb * wya;
                float w10 = wxa * wyb, w11 = wxb * wyb;
                bool i00 = (unsigned)ly0     < (unsigned)TS && (unsigned)lx0     < (unsigned)TS && w00 != 0.f;
                bool i01 = (unsigned)ly0     < (unsigned)TS && (unsigned)(lx0+1) < (unsigned)TS && w01 != 0.f;
                bool i10 = (unsigned)(ly0+1) < (unsigned)TS && (unsigned)lx0     < (unsigned)TS && w10 != 0.f;
                bool i11 = (unsigned)(ly0+1) < (unsigned)TS && (unsigned)(lx0+1) < (unsigned)TS && w11 != 0.f;
                if (i00 | i01 | i10 | i11) {
                    // im0 loads only when this pixel actually contributes
                    int p_ = (ayp << 10) + axp;
                    float sv0 = imb[p_]          * SCALE;
                    float sv1 = imb[HW + p_]     * SCALE;
                    float sv2 = imb[2 * HW + p_] * SCALE;
#define CORNER(II, C, W)                                                       \
    if (II) {                                                                  \
        unsigned lo1 = (unsigned)__float2int_rz(sv0 * (W)) + BIAS_I;           \
        unsigned long long a1 =                                                \
            ((unsigned long long)(unsigned)__float2int_rz(sv1 * (W)) << 32) |  \
            (unsigned long long)lo1;                                           \
        unsigned long long a2 =                                                \
            ((unsigned long long)(unsigned)__float2int_rz(sv2 * (W)) << 32) |  \
            1ull;                                                              \
        atomicAdd(&s_w1[C], a1);                                               \
        atomicAdd(&s_w2[C], a2);                                               \
    }
                    CORNER(i00, ly0 * TS + lx0,           w00)
                    CORNER(i01, ly0 * TS + lx0 + 1,       w01)
                    CORNER(i10, (ly0 + 1) * TS + lx0,     w10)
                    CORNER(i11, (ly0 + 1) * TS + lx0 + 1, w11)
#undef CORNER
                }
            }
        }
        i = ni; wy = nwy; wx = nwx;
        fA = fB; axp = bxp; ayp = byp;
    }
    __syncthreads();

    float* accb = acc + (size_t)b * Cn * HW;
    const int lane = threadIdx.x & 63;
    for (int i2 = threadIdx.x; i2 < TS * TS; i2 += 1024) {
        unsigned long long w1 = s_w1[i2], w2 = s_w2[i2];
        unsigned n  = (unsigned)w2;                       // event count
        int c0 = (int)((unsigned)w1 - n * BIAS_I);        // exact bias removal
        int c1 = (int)(unsigned)(w1 >> 32);
        int c2 = (int)(unsigned)(w2 >> 32);
        int row = i2 >> 6;                    // wave <-> one 64-px tile row
        int p = ((ty + row) << 10) + tx + (i2 & 63);
        accb[p]          = (float)c0 * INVSC;
        accb[HW + p]     = (float)c1 * INVSC;
        accb[2 * HW + p] = (float)c2 * INVSC;
        unsigned long long m = __ballot(n != 0);
        int wbase = (b * HW + ((ty + row) << 10) + tx) >> 5;
        if (lane == 0)  wm[wbase]     = (unsigned)m;
        if (lane == 32) wm[wbase + 1] = (unsigned)(m >> 32);
    }
}

// ------- fallback: walk the compact |flow|>FMAX list, scattered atomics -----
// runs AFTER owner flush (stream-ordered); planes are float by then; mask bit
// OR preserves the !=0 hole semantics (only set when w != 0).
__global__ __launch_bounds__(BLK) void splat_fallback(
    const float* __restrict__ im0, const float* __restrict__ flow,
    float* __restrict__ acc, unsigned* __restrict__ wm,
    const unsigned* __restrict__ fb_count, const unsigned* __restrict__ fb_list)
{
    int n = (int)*fb_count; if (n > FB_CAP) n = FB_CAP;
    for (int t = blockIdx.x * BLK + threadIdx.x; t < n; t += gridDim.x * BLK) {
        unsigned idx = fb_list[t];
        int b = idx >> 20;
        int p = idx & (HW - 1);
        int y = p >> 10;
        int x = p & (Wn - 1);
        float2 f = reinterpret_cast<const float2*>(flow)[idx];
        float X = (float)x + f.x;
        float Y = (float)y + f.y;
        float x0 = floorf(X), y0 = floorf(Y);
        float v0 = im0[(b * Cn + 0) * HW + p];
        float v1 = im0[(b * Cn + 1) * HW + p];
        float v2 = im0[(b * Cn + 2) * HW + p];
#pragma unroll
        for (int cy = 0; cy < 2; ++cy) {
#pragma unroll
            for (int cx = 0; cx < 2; ++cx) {
                float xi = x0 + (float)cx;
                float yi = y0 + (float)cy;
                if (xi < 0.f || xi > (float)(Wn - 1) ||
                    yi < 0.f || yi > (float)(Hn - 1)) continue;
                float w = (1.f - fabsf(X - xi)) * (1.f - fabsf(Y - yi));
                if (w == 0.f) continue;
                int di = (int)yi * Wn + (int)xi;
                int gi = b * HW + di;
                atomicOr(&wm[gi >> 5], 1u << (gi & 31));
                atomicAdd(&acc[(b * Cn + 0) * HW + di], v0 * w);
                atomicAdd(&acc[(b * Cn + 1) * HW + di], v1 * w);
                atomicAdd(&acc[(b * Cn + 2) * HW + di], v2 * w);
            }
        }
    }
}

// ------- infill iteration: dst = where(hole, gather(src,flowback), src) -----
// 4 px/thread float4, grid-stride; gather only at holes (~2-3%).
__global__ __launch_bounds__(BLK) void infill_kernel(
    const float* __restrict__ src, const unsigned* __restrict__ wm,
    const float* __restrict__ flowback, float* __restrict__ dst,
    const int* __restrict__ n_iter, int iter)
{
    int n = *n_iter; if (n > MAX_ITERS) n = MAX_ITERS;
    if (iter >= n) return;

    for (int q = blockIdx.x * BLK + threadIdx.x; q < BHW / 4;
         q += gridDim.x * BLK) {
        int idx = q * 4;
        int b = idx >> 20;
        int p = idx & (HW - 1);

        const float* sb = src + (size_t)b * Cn * HW;
        unsigned nib = (wm[idx >> 5] >> (idx & 31)) & 0xFu;
        float4 o0 = *reinterpret_cast<const float4*>(&sb[p]);
        float4 o1 = *reinterpret_cast<const float4*>(&sb[HW + p]);
        float4 o2 = *reinterpret_cast<const float4*>(&sb[2 * HW + p]);

        if (nib != 0xFu) {
            int y = p >> 10, x = p & (Wn - 1);
            const float2* fbp = reinterpret_cast<const float2*>(flowback) + idx;
            float* o0a = reinterpret_cast<float*>(&o0);
            float* o1a = reinterpret_cast<float*>(&o1);
            float* o2a = reinterpret_cast<float*>(&o2);
#pragma unroll
            for (int k = 0; k < 4; ++k) {
                if ((nib >> k) & 1u) continue;
                float2 f = fbp[k];
                float X = (float)(x + k) + f.x;
                float Y = (float)y + f.y;
                float x0 = floorf(X), y0 = floorf(Y);
                float g0 = 0.f, g1 = 0.f, g2 = 0.f;
#pragma unroll
                for (int cy = 0; cy < 2; ++cy) {
#pragma unroll
                    for (int cx = 0; cx < 2; ++cx) {
                        float xi = x0 + (float)cx;
                        float yi = y0 + (float)cy;
                        if (xi < 0.f || xi > (float)(Wn - 1) ||
                            yi < 0.f || yi > (float)(Hn - 1)) continue;
                        float w = (1.f - fabsf(X - xi)) * (1.f - fabsf(Y - yi));
                        int gi = (int)yi * Wn + (int)xi;
                        g0 += sb[gi] * w;
                        g1 += sb[HW + gi] * w;
                        g2 += sb[2 * HW + gi] * w;
                    }
                }
                o0a[k] = g0; o1a[k] = g1; o2a[k] = g2;
            }
        }
        float* db = dst + (size_t)b * Cn * HW;
        *reinterpret_cast<float4*>(&db[p])          = o0;
        *reinterpret_cast<float4*>(&db[HW + p])     = o1;
        *reinterpret_cast<float4*>(&db[2 * HW + p]) = o2;
    }
}

// ------- if iteration count even (incl. 0), result sits in acc: copy out -----
__global__ __launch_bounds__(BLK) void copy_even_kernel(
    const float* __restrict__ A, float* __restrict__ dst,
    const int* __restrict__ n_iter)
{
    int n = *n_iter; if (n > MAX_ITERS) n = MAX_ITERS;
    if (n & 1) return;   // odd: result already in dst
    for (int q = blockIdx.x * BLK + threadIdx.x; q < BCHW / 4;
         q += gridDim.x * BLK) {
        int i = q * 4;
        *reinterpret_cast<float4*>(&dst[i]) =
            *reinterpret_cast<const float4*>(&A[i]);
    }
}

extern "C" void kernel_launch(void* const* d_in, const int* in_sizes, int n_in,
                              void* d_out, int out_size, void* d_ws, size_t ws_size,
                              hipStream_t stream)
{
    const float* im0      = (const float*)d_in[0];
    const float* flow     = (const float*)d_in[1];
    const float* flowback = (const float*)d_in[2];
    const int*   n_iter   = (const int*)d_in[3];
    float* out = (float*)d_out;
    float* acc = (float*)d_ws;                       // BCHW floats (50.3 MB)
    unsigned* wm = (unsigned*)(acc + BCHW);          // BHW/32 mask words (0.5 MB)
    unsigned* fb_count = wm + BHW / 32;              // 1 word (+pad)
    unsigned* fb_list  = fb_count + 16;              // FB_CAP words (2 MB)

    hipMemsetAsync(fb_count, 0, sizeof(unsigned), stream);

    // owner splat writes every acc element and every mask word -> no memset
    splat_owner<<<Bn * 256, 1024, 0, stream>>>(im0, flow, acc, wm,
                                               fb_count, fb_list);

    splat_fallback<<<128, BLK, 0, stream>>>(im0, flow, acc, wm,
                                            fb_count, fb_list);

    // ping-pong: iter 0: acc->out, iter 1: out->acc, ...
    // iters >=1 get small grids (grid-stride keeps them correct if n>1;
    // benchmark input has n==1 so they are gated no-ops)
    for (int i = 0; i < MAX_ITERS; ++i) {
        const float* s = (i % 2 == 0) ? acc : out;
        float*       d = (i % 2 == 0) ? out : acc;
        int g = (i == 0) ? 2048 : 264;
        infill_kernel<<<g, BLK, 0, stream>>>(s, wm, flowback, d, n_iter, i);
    }

    copy_even_kernel<<<264, BLK, 0, stream>>>(acc, out, n_iter);
}

// Round 8
// 416.560 us; speedup vs baseline: 1.0088x; 1.0088x over previous
//
#include <hip/hip_runtime.h>

#define BLK 256

constexpr int Bn = 4, Cn = 3, Hn = 1024, Wn = 1024;
constexpr int HW   = Hn * Wn;        // 1<<20
constexpr int BHW  = Bn * HW;        // 4,194,304
constexpr int BCHW = Bn * Cn * HW;   // 12,582,912
constexpr int MAX_ITERS = 4;

// dest-tile ownership splat
constexpr int TS  = 64;              // dest tile side
constexpr int Mg  = 24;              // source window margin
constexpr int WND = TS + 2 * Mg;     // 112
constexpr int NW  = WND * WND;       // 12544
constexpr float FMAX = 23.0f;        // = Mg-1; owner handles |f|<=FMAX exactly

// u32 fixed point with bias-packed event count (R7 post-mortem: u64 LDS
// atomicAdd is NOT native-fast on gfx950 -> 6x regression; back to ds_add_u32
// only). Channel0 accumulator: sum of (q0 + 2^19) per event; at flush
// n = (s0 + 2^18) >> 19 (exact while |sum q0| < 2^18: q0 = v*8192*w, needs
// |sum v*w| < 32 per cell -- ~11 sigma for N(0,1) data), c0 = s0 - n*2^19.
// n doubles as the hole flag -> 3 DS atomics per corner, no flag store.
constexpr float SCALE = 8192.0f;                 // 2^13
constexpr float INVSC = 1.220703125e-04f;        // 2^-13 exact
constexpr unsigned BIAS_I = 524288u;             // 2^19 (n<=2304 -> no u32 ovf)

constexpr int FB_CAP = 1 << 19;      // fallback list capacity (16x margin)

// flow-only prefetch; sentinel 1e9 fails the FMAX test for out-of-image px
#define STAGEF(PRED, WY, WX, F, PX, PY)                                       \
    {   PY = ty - Mg + (WY);                                                  \
        PX = tx - Mg + (WX);                                                  \
        F = make_float2(1e9f, 1e9f);                                          \
        if ((PRED) && (unsigned)PY < (unsigned)Hn &&                          \
            (unsigned)PX < (unsigned)Wn)                                      \
            F = flb[(PY << 10) + PX];                                         \
    }

__global__ __launch_bounds__(1024, 8) void splat_owner(
    const float* __restrict__ im0, const float* __restrict__ flow,
    float* __restrict__ acc, unsigned* __restrict__ wm,
    unsigned* __restrict__ fb_count, unsigned* __restrict__ fb_list)
{
    __shared__ unsigned s0a[TS * TS];   // c0*2^13 + n*2^19
    __shared__ unsigned s1a[TS * TS];   // c1*2^13
    __shared__ unsigned s2a[TS * TS];   // c2*2^13          (48 KiB total)
    // XCD-bijective swizzle (1024 blocks, 8 XCDs): contiguous tile rows/XCD
    const int bid  = ((blockIdx.x & 7) << 7) | (blockIdx.x >> 3);
    const int b    = bid >> 8;        // 256 tiles per batch (16x16)
    const int tile = bid & 255;
    const int ty   = (tile >> 4) * TS;
    const int tx   = (tile & 15) * TS;

    for (int i = threadIdx.x; i < TS * TS; i += 1024) {
        s0a[i] = 0u; s1a[i] = 0u; s2a[i] = 0u;
    }
    __syncthreads();

    const float*  imb = im0 + (size_t)b * Cn * HW;
    const float2* flb = reinterpret_cast<const float2*>(flow) + (size_t)b * HW;

    int i  = threadIdx.x;
    int wy = i / WND, wx = i - wy * WND;      // one-time div (i < 1024)
    int axp, ayp; float2 fA;
    STAGEF(true, wy, wx, fA, axp, ayp);

    while (i < NW) {
        int ni  = i + 1024;
        int nwx = wx + (1024 % WND);          // +16
        int nwy = wy + (1024 / WND);          // +9
        if (nwx >= WND) { nwx -= WND; ++nwy; }
        // prefetch next visit's flow before processing this one
        int bxp, byp; float2 fB;
        STAGEF(ni < NW, nwy, nwx, fB, bxp, byp);

        bool small_f = (fabsf(fA.x) <= FMAX && fabsf(fA.y) <= FMAX);

        // fallback detection: each image px is in exactly one tile's core;
        // its owner appends it to the compact list (~33K appends total).
        bool in_core = (wy >= Mg && wy < Mg + TS && wx >= Mg && wx < Mg + TS);
        if (__any(in_core && !small_f)) {
            if (in_core && !small_f) {
                unsigned slot = atomicAdd(fb_count, 1u);
                if (slot < (unsigned)FB_CAP)
                    fb_list[slot] = (unsigned)(b * HW + (ayp << 10) + axp);
            }
        }

        if (small_f) {
            float X = (float)axp + fA.x;
            float Y = (float)ayp + fA.y;
            float x0 = floorf(X), y0 = floorf(Y);
            int lx0 = (int)x0 - tx;
            int ly0 = (int)y0 - ty;
            // box reject: any of the 2x2 corners inside this tile?
            if (lx0 >= -1 && lx0 < TS && ly0 >= -1 && ly0 < TS) {
                // shared bilinear factors; per-corner product identical to ref
                float wxa = 1.f - fabsf(X - x0);
                float wxb = 1.f - fabsf(X - (x0 + 1.f));
                float wya = 1.f - fabsf(Y - y0);
                float wyb = 1.f - fabsf(Y - (y0 + 1.f));
                float w00 = wxa * wya, w01 = wxb * wya;
                float w10 = wxa * wyb, w11 = wxb * wyb;
                bool i00 = (unsigned)ly0     < (unsigned)TS && (unsigned)lx0     < (unsigned)TS && w00 != 0.f;
                bool i01 = (unsigned)ly0     < (unsigned)TS && (unsigned)(lx0+1) < (unsigned)TS && w01 != 0.f;
                bool i10 = (unsigned)(ly0+1) < (unsigned)TS && (unsigned)lx0     < (unsigned)TS && w10 != 0.f;
                bool i11 = (unsigned)(ly0+1) < (unsigned)TS && (unsigned)(lx0+1) < (unsigned)TS && w11 != 0.f;
                if (i00 | i01 | i10 | i11) {
                    // im0 loads only when this pixel actually contributes
                    int p_ = (ayp << 10) + axp;
                    float sv0 = imb[p_]          * SCALE;
                    float sv1 = imb[HW + p_]     * SCALE;
                    float sv2 = imb[2 * HW + p_] * SCALE;
#define CORNER(II, C, W)                                                       \
    if (II) {                                                                  \
        int c_ = (C);                                                          \
        atomicAdd(&s0a[c_], (unsigned)__float2int_rz(sv0 * (W)) + BIAS_I);     \
        atomicAdd(&s1a[c_], (unsigned)__float2int_rz(sv1 * (W)));              \
        atomicAdd(&s2a[c_], (unsigned)__float2int_rz(sv2 * (W)));              \
    }
                    CORNER(i00, ly0 * TS + lx0,           w00)
                    CORNER(i01, ly0 * TS + lx0 + 1,       w01)
                    CORNER(i10, (ly0 + 1) * TS + lx0,     w10)
                    CORNER(i11, (ly0 + 1) * TS + lx0 + 1, w11)
#undef CORNER
                }
            }
        }
        i = ni; wy = nwy; wx = nwx;
        fA = fB; axp = bxp; ayp = byp;
    }
    __syncthreads();

    float* accb = acc + (size_t)b * Cn * HW;
    const int lane = threadIdx.x & 63;
    for (int i2 = threadIdx.x; i2 < TS * TS; i2 += 1024) {
        unsigned a0 = s0a[i2];
        unsigned n  = (a0 + 262144u) >> 19;               // event count
        int c0 = (int)(a0 - (n << 19));                   // exact bias removal
        int c1 = (int)s1a[i2];
        int c2 = (int)s2a[i2];
        int row = i2 >> 6;                    // wave <-> one 64-px tile row
        int p = ((ty + row) << 10) + tx + (i2 & 63);
        accb[p]          = (float)c0 * INVSC;
        accb[HW + p]     = (float)c1 * INVSC;
        accb[2 * HW + p] = (float)c2 * INVSC;
        unsigned long long m = __ballot(n != 0);
        int wbase = (b * HW + ((ty + row) << 10) + tx) >> 5;
        if (lane == 0)  wm[wbase]     = (unsigned)m;
        if (lane == 32) wm[wbase + 1] = (unsigned)(m >> 32);
    }
}

// ------- fallback: walk the compact |flow|>FMAX list, scattered atomics -----
// runs AFTER owner flush (stream-ordered); planes are float by then; mask bit
// OR preserves the !=0 hole semantics (only set when w != 0).
__global__ __launch_bounds__(BLK) void splat_fallback(
    const float* __restrict__ im0, const float* __restrict__ flow,
    float* __restrict__ acc, unsigned* __restrict__ wm,
    const unsigned* __restrict__ fb_count, const unsigned* __restrict__ fb_list)
{
    int n = (int)*fb_count; if (n > FB_CAP) n = FB_CAP;
    for (int t = blockIdx.x * BLK + threadIdx.x; t < n; t += gridDim.x * BLK) {
        unsigned idx = fb_list[t];
        int b = idx >> 20;
        int p = idx & (HW - 1);
        int y = p >> 10;
        int x = p & (Wn - 1);
        float2 f = reinterpret_cast<const float2*>(flow)[idx];
        float X = (float)x + f.x;
        float Y = (float)y + f.y;
        float x0 = floorf(X), y0 = floorf(Y);
        float v0 = im0[(b * Cn + 0) * HW + p];
        float v1 = im0[(b * Cn + 1) * HW + p];
        float v2 = im0[(b * Cn + 2) * HW + p];
#pragma unroll
        for (int cy = 0; cy < 2; ++cy) {
#pragma unroll
            for (int cx = 0; cx < 2; ++cx) {
                float xi = x0 + (float)cx;
                float yi = y0 + (float)cy;
                if (xi < 0.f || xi > (float)(Wn - 1) ||
                    yi < 0.f || yi > (float)(Hn - 1)) continue;
                float w = (1.f - fabsf(X - xi)) * (1.f - fabsf(Y - yi));
                if (w == 0.f) continue;
                int di = (int)yi * Wn + (int)xi;
                int gi = b * HW + di;
                atomicOr(&wm[gi >> 5], 1u << (gi & 31));
                atomicAdd(&acc[(b * Cn + 0) * HW + di], v0 * w);
                atomicAdd(&acc[(b * Cn + 1) * HW + di], v1 * w);
                atomicAdd(&acc[(b * Cn + 2) * HW + di], v2 * w);
            }
        }
    }
}

// ------- infill iteration: dst = where(hole, gather(src,flowback), src) -----
// 4 px/thread float4, grid-stride; gather only at holes (~2-3%).
__global__ __launch_bounds__(BLK) void infill_kernel(
    const float* __restrict__ src, const unsigned* __restrict__ wm,
    const float* __restrict__ flowback, float* __restrict__ dst,
    const int* __restrict__ n_iter, int iter)
{
    int n = *n_iter; if (n > MAX_ITERS) n = MAX_ITERS;
    if (iter >= n) return;

    for (int q = blockIdx.x * BLK + threadIdx.x; q < BHW / 4;
         q += gridDim.x * BLK) {
        int idx = q * 4;
        int b = idx >> 20;
        int p = idx & (HW - 1);

        const float* sb = src + (size_t)b * Cn * HW;
        unsigned nib = (wm[idx >> 5] >> (idx & 31)) & 0xFu;
        float4 o0 = *reinterpret_cast<const float4*>(&sb[p]);
        float4 o1 = *reinterpret_cast<const float4*>(&sb[HW + p]);
        float4 o2 = *reinterpret_cast<const float4*>(&sb[2 * HW + p]);

        if (nib != 0xFu) {
            int y = p >> 10, x = p & (Wn - 1);
            const float2* fbp = reinterpret_cast<const float2*>(flowback) + idx;
            float* o0a = reinterpret_cast<float*>(&o0);
            float* o1a = reinterpret_cast<float*>(&o1);
            float* o2a = reinterpret_cast<float*>(&o2);
#pragma unroll
            for (int k = 0; k < 4; ++k) {
                if ((nib >> k) & 1u) continue;
                float2 f = fbp[k];
                float X = (float)(x + k) + f.x;
                float Y = (float)y + f.y;
                float x0 = floorf(X), y0 = floorf(Y);
                float g0 = 0.f, g1 = 0.f, g2 = 0.f;
#pragma unroll
                for (int cy = 0; cy < 2; ++cy) {
#pragma unroll
                    for (int cx = 0; cx < 2; ++cx) {
                        float xi = x0 + (float)cx;
                        float yi = y0 + (float)cy;
                        if (xi < 0.f || xi > (float)(Wn - 1) ||
                            yi < 0.f || yi > (float)(Hn - 1)) continue;
                        float w = (1.f - fabsf(X - xi)) * (1.f - fabsf(Y - yi));
                        int gi = (int)yi * Wn + (int)xi;
                        g0 += sb[gi] * w;
                        g1 += sb[HW + gi] * w;
                        g2 += sb[2 * HW + gi] * w;
                    }
                }
                o0a[k] = g0; o1a[k] = g1; o2a[k] = g2;
            }
        }
        float* db = dst + (size_t)b * Cn * HW;
        *reinterpret_cast<float4*>(&db[p])          = o0;
        *reinterpret_cast<float4*>(&db[HW + p])     = o1;
        *reinterpret_cast<float4*>(&db[2 * HW + p]) = o2;
    }
}

// ------- if iteration count even (incl. 0), result sits in acc: copy out -----
__global__ __launch_bounds__(BLK) void copy_even_kernel(
    const float* __restrict__ A, float* __restrict__ dst,
    const int* __restrict__ n_iter)
{
    int n = *n_iter; if (n > MAX_ITERS) n = MAX_ITERS;
    if (n & 1) return;   // odd: result already in dst
    for (int q = blockIdx.x * BLK + threadIdx.x; q < BCHW / 4;
         q += gridDim.x * BLK) {
        int i = q * 4;
        *reinterpret_cast<float4*>(&dst[i]) =
            *reinterpret_cast<const float4*>(&A[i]);
    }
}

extern "C" void kernel_launch(void* const* d_in, const int* in_sizes, int n_in,
                              void* d_out, int out_size, void* d_ws, size_t ws_size,
                              hipStream_t stream)
{
    const float* im0      = (const float*)d_in[0];
    const float* flow     = (const float*)d_in[1];
    const float* flowback = (const float*)d_in[2];
    const int*   n_iter   = (const int*)d_in[3];
    float* out = (float*)d_out;
    float* acc = (float*)d_ws;                       // BCHW floats (50.3 MB)
    unsigned* wm = (unsigned*)(acc + BCHW);          // BHW/32 mask words (0.5 MB)
    unsigned* fb_count = wm + BHW / 32;              // 1 word (+pad)
    unsigned* fb_list  = fb_count + 16;              // FB_CAP words (2 MB)

    hipMemsetAsync(fb_count, 0, sizeof(unsigned), stream);

    // owner splat writes every acc element and every mask word -> no memset
    splat_owner<<<Bn * 256, 1024, 0, stream>>>(im0, flow, acc, wm,
                                               fb_count, fb_list);

    splat_fallback<<<128, BLK, 0, stream>>>(im0, flow, acc, wm,
                                            fb_count, fb_list);

    // ping-pong: iter 0: acc->out, iter 1: out->acc, ...
    // iters >=1 get small grids (grid-stride keeps them correct if n>1;
    // benchmark input has n==1 so they are gated no-ops)
    for (int i = 0; i < MAX_ITERS; ++i) {
        const float* s = (i % 2 == 0) ? acc : out;
        float*       d = (i % 2 == 0) ? out : acc;
        int g = (i == 0) ? 2048 : 264;
        infill_kernel<<<g, BLK, 0, stream>>>(s, wm, flowback, d, n_iter, i);
    }

    copy_even_kernel<<<264, BLK, 0, stream>>>(acc, out, n_iter);
}

// Round 9
// 121.245 us; speedup vs baseline: 3.4660x; 3.4357x over previous
//
#include <hip/hip_runtime.h>

#define BLK 256

constexpr int Bn = 4, Cn = 3, Hn = 1024, Wn = 1024;
constexpr int HW   = Hn * Wn;        // 1<<20
constexpr int BHW  = Bn * HW;        // 4,194,304
constexpr int BCHW = Bn * Cn * HW;   // 12,582,912
constexpr int MAX_ITERS = 4;

// dest-tile ownership splat
constexpr int TS  = 64;              // dest tile side
constexpr int Mg  = 24;              // source window margin
constexpr int WND = TS + 2 * Mg;     // 112
constexpr int NW  = WND * WND;       // 12544
constexpr float FMAX = 23.0f;        // = Mg-1; owner handles |f|<=FMAX exactly

// u32 fixed point with bias-packed event count. Channel0 accumulator holds
// sum of (q0 + 2^19) per event; flush: n = (s0 + 2^18) >> 19, c0 = s0 - n*2^19
// (exact while |sum v0*w| < 32 per cell, ~11 sigma for N(0,1)). n>0 == hole
// flag -> 3 ds_add_u32 per corner, no flag store.
constexpr float SCALE = 8192.0f;                 // 2^13
constexpr float INVSC = 1.220703125e-04f;        // 2^-13 exact
constexpr unsigned BIAS_I = 524288u;             // 2^19 (n<=2304 -> no u32 ovf)

constexpr int FB_CAP = 1 << 19;      // global fallback list capacity
constexpr int FB_LDS = 2048;         // per-block LDS staging (core=4096px@0.8%
                                     // -> ~33 expected; 60x margin)

// flow-only prefetch; sentinel 1e9 fails the FMAX test for out-of-image px
#define STAGEF(PRED, WY, WX, F, PX, PY)                                       \
    {   PY = ty - Mg + (WY);                                                  \
        PX = tx - Mg + (WX);                                                  \
        F = make_float2(1e9f, 1e9f);                                          \
        if ((PRED) && (unsigned)PY < (unsigned)Hn &&                          \
            (unsigned)PX < (unsigned)Wn)                                      \
            F = flb[(PY << 10) + PX];                                         \
    }

__global__ __launch_bounds__(1024, 8) void splat_owner(
    const float* __restrict__ im0, const float* __restrict__ flow,
    float* __restrict__ acc, unsigned* __restrict__ wm,
    unsigned* __restrict__ fb_count, unsigned* __restrict__ fb_list)
{
    __shared__ unsigned s0a[TS * TS];   // c0*2^13 + n*2^19
    __shared__ unsigned s1a[TS * TS];   // c1*2^13
    __shared__ unsigned s2a[TS * TS];   // c2*2^13          (48 KiB)
    __shared__ unsigned s_fb[FB_LDS];   // fallback px staging (8 KiB)
    __shared__ unsigned s_fbc, s_base;
    // XCD-bijective swizzle (1024 blocks, 8 XCDs): contiguous tile rows/XCD
    const int bid  = ((blockIdx.x & 7) << 7) | (blockIdx.x >> 3);
    const int b    = bid >> 8;        // 256 tiles per batch (16x16)
    const int tile = bid & 255;
    const int ty   = (tile >> 4) * TS;
    const int tx   = (tile & 15) * TS;

    for (int i = threadIdx.x; i < TS * TS; i += 1024) {
        s0a[i] = 0u; s1a[i] = 0u; s2a[i] = 0u;
    }
    if (threadIdx.x == 0) s_fbc = 0u;
    __syncthreads();

    const float*  imb = im0 + (size_t)b * Cn * HW;
    const float2* flb = reinterpret_cast<const float2*>(flow) + (size_t)b * HW;

    int i  = threadIdx.x;
    int wy = i / WND, wx = i - wy * WND;      // one-time div (i < 1024)
    int axp, ayp; float2 fA;
    STAGEF(true, wy, wx, fA, axp, ayp);

    while (i < NW) {
        int ni  = i + 1024;
        int nwx = wx + (1024 % WND);          // +16
        int nwy = wy + (1024 / WND);          // +9
        if (nwx >= WND) { nwx -= WND; ++nwy; }
        // prefetch next visit's flow before processing this one
        int bxp, byp; float2 fB;
        STAGEF(ni < NW, nwy, nwx, fB, bxp, byp);

        bool small_f = (fabsf(fA.x) <= FMAX && fabsf(fA.y) <= FMAX);

        // fallback detection via LDS append (R8 post-mortem: the in-loop
        // single-address GLOBAL atomic was the 6x regression -- ~80K
        // contended L2 RMWs + vmcnt drains. LDS atomic is block-local.)
        bool in_core = (wy >= Mg && wy < Mg + TS && wx >= Mg && wx < Mg + TS);
        if (in_core && !small_f) {
            unsigned k = atomicAdd(&s_fbc, 1u);
            unsigned gidx = (unsigned)(b * HW + (ayp << 10) + axp);
            if (k < (unsigned)FB_LDS) {
                s_fb[k] = gidx;
            } else {                       // overflow: never on bench data
                unsigned slot = atomicAdd(fb_count, 1u);
                if (slot < (unsigned)FB_CAP) fb_list[slot] = gidx;
            }
        }

        if (small_f) {
            float X = (float)axp + fA.x;
            float Y = (float)ayp + fA.y;
            float x0 = floorf(X), y0 = floorf(Y);
            int lx0 = (int)x0 - tx;
            int ly0 = (int)y0 - ty;
            // box reject: any of the 2x2 corners inside this tile?
            if (lx0 >= -1 && lx0 < TS && ly0 >= -1 && ly0 < TS) {
                // shared bilinear factors; per-corner product identical to ref
                float wxa = 1.f - fabsf(X - x0);
                float wxb = 1.f - fabsf(X - (x0 + 1.f));
                float wya = 1.f - fabsf(Y - y0);
                float wyb = 1.f - fabsf(Y - (y0 + 1.f));
                float w00 = wxa * wya, w01 = wxb * wya;
                float w10 = wxa * wyb, w11 = wxb * wyb;
                bool i00 = (unsigned)ly0     < (unsigned)TS && (unsigned)lx0     < (unsigned)TS && w00 != 0.f;
                bool i01 = (unsigned)ly0     < (unsigned)TS && (unsigned)(lx0+1) < (unsigned)TS && w01 != 0.f;
                bool i10 = (unsigned)(ly0+1) < (unsigned)TS && (unsigned)lx0     < (unsigned)TS && w10 != 0.f;
                bool i11 = (unsigned)(ly0+1) < (unsigned)TS && (unsigned)(lx0+1) < (unsigned)TS && w11 != 0.f;
                if (i00 | i01 | i10 | i11) {
                    // im0 loads only when this pixel actually contributes
                    int p_ = (ayp << 10) + axp;
                    float sv0 = imb[p_]          * SCALE;
                    float sv1 = imb[HW + p_]     * SCALE;
                    float sv2 = imb[2 * HW + p_] * SCALE;
#define CORNER(II, C, W)                                                       \
    if (II) {                                                                  \
        int c_ = (C);                                                          \
        atomicAdd(&s0a[c_], (unsigned)__float2int_rz(sv0 * (W)) + BIAS_I);     \
        atomicAdd(&s1a[c_], (unsigned)__float2int_rz(sv1 * (W)));              \
        atomicAdd(&s2a[c_], (unsigned)__float2int_rz(sv2 * (W)));              \
    }
                    CORNER(i00, ly0 * TS + lx0,           w00)
                    CORNER(i01, ly0 * TS + lx0 + 1,       w01)
                    CORNER(i10, (ly0 + 1) * TS + lx0,     w10)
                    CORNER(i11, (ly0 + 1) * TS + lx0 + 1, w11)
#undef CORNER
                }
            }
        }
        i = ni; wy = nwy; wx = nwx;
        fA = fB; axp = bxp; ayp = byp;
    }
    __syncthreads();

    // one global reservation per block, then coalesced list flush
    if (threadIdx.x == 0 && s_fbc != 0u) {
        unsigned cnt = s_fbc < (unsigned)FB_LDS ? s_fbc : (unsigned)FB_LDS;
        s_base = atomicAdd(fb_count, cnt);
    }
    __syncthreads();
    {
        unsigned cnt = s_fbc < (unsigned)FB_LDS ? s_fbc : (unsigned)FB_LDS;
        for (unsigned k = threadIdx.x; k < cnt; k += 1024) {
            unsigned slot = s_base + k;
            if (slot < (unsigned)FB_CAP) fb_list[slot] = s_fb[k];
        }
    }

    float* accb = acc + (size_t)b * Cn * HW;
    const int lane = threadIdx.x & 63;
    for (int i2 = threadIdx.x; i2 < TS * TS; i2 += 1024) {
        unsigned a0 = s0a[i2];
        unsigned n  = (a0 + 262144u) >> 19;               // event count
        int c0 = (int)(a0 - (n << 19));                   // exact bias removal
        int c1 = (int)s1a[i2];
        int c2 = (int)s2a[i2];
        int row = i2 >> 6;                    // wave <-> one 64-px tile row
        int p = ((ty + row) << 10) + tx + (i2 & 63);
        accb[p]          = (float)c0 * INVSC;
        accb[HW + p]     = (float)c1 * INVSC;
        accb[2 * HW + p] = (float)c2 * INVSC;
        unsigned long long m = __ballot(n != 0);
        int wbase = (b * HW + ((ty + row) << 10) + tx) >> 5;
        if (lane == 0)  wm[wbase]     = (unsigned)m;
        if (lane == 32) wm[wbase + 1] = (unsigned)(m >> 32);
    }
}

// ------- fallback: walk the compact |flow|>FMAX list, scattered atomics -----
// runs AFTER owner flush (stream-ordered); planes are float by then; mask bit
// OR preserves the !=0 hole semantics (only set when w != 0).
__global__ __launch_bounds__(BLK) void splat_fallback(
    const float* __restrict__ im0, const float* __restrict__ flow,
    float* __restrict__ acc, unsigned* __restrict__ wm,
    const unsigned* __restrict__ fb_count, const unsigned* __restrict__ fb_list)
{
    int n = (int)*fb_count; if (n > FB_CAP) n = FB_CAP;
    for (int t = blockIdx.x * BLK + threadIdx.x; t < n; t += gridDim.x * BLK) {
        unsigned idx = fb_list[t];
        int b = idx >> 20;
        int p = idx & (HW - 1);
        int y = p >> 10;
        int x = p & (Wn - 1);
        float2 f = reinterpret_cast<const float2*>(flow)[idx];
        float X = (float)x + f.x;
        float Y = (float)y + f.y;
        float x0 = floorf(X), y0 = floorf(Y);
        float v0 = im0[(b * Cn + 0) * HW + p];
        float v1 = im0[(b * Cn + 1) * HW + p];
        float v2 = im0[(b * Cn + 2) * HW + p];
#pragma unroll
        for (int cy = 0; cy < 2; ++cy) {
#pragma unroll
            for (int cx = 0; cx < 2; ++cx) {
                float xi = x0 + (float)cx;
                float yi = y0 + (float)cy;
                if (xi < 0.f || xi > (float)(Wn - 1) ||
                    yi < 0.f || yi > (float)(Hn - 1)) continue;
                float w = (1.f - fabsf(X - xi)) * (1.f - fabsf(Y - yi));
                if (w == 0.f) continue;
                int di = (int)yi * Wn + (int)xi;
                int gi = b * HW + di;
                atomicOr(&wm[gi >> 5], 1u << (gi & 31));
                atomicAdd(&acc[(b * Cn + 0) * HW + di], v0 * w);
                atomicAdd(&acc[(b * Cn + 1) * HW + di], v1 * w);
                atomicAdd(&acc[(b * Cn + 2) * HW + di], v2 * w);
            }
        }
    }
}

// ------- infill iteration: dst = where(hole, gather(src,flowback), src) -----
// 4 px/thread float4, grid-stride; gather only at holes (~2-3%).
__global__ __launch_bounds__(BLK) void infill_kernel(
    const float* __restrict__ src, const unsigned* __restrict__ wm,
    const float* __restrict__ flowback, float* __restrict__ dst,
    const int* __restrict__ n_iter, int iter)
{
    int n = *n_iter; if (n > MAX_ITERS) n = MAX_ITERS;
    if (iter >= n) return;

    for (int q = blockIdx.x * BLK + threadIdx.x; q < BHW / 4;
         q += gridDim.x * BLK) {
        int idx = q * 4;
        int b = idx >> 20;
        int p = idx & (HW - 1);

        const float* sb = src + (size_t)b * Cn * HW;
        unsigned nib = (wm[idx >> 5] >> (idx & 31)) & 0xFu;
        float4 o0 = *reinterpret_cast<const float4*>(&sb[p]);
        float4 o1 = *reinterpret_cast<const float4*>(&sb[HW + p]);
        float4 o2 = *reinterpret_cast<const float4*>(&sb[2 * HW + p]);

        if (nib != 0xFu) {
            int y = p >> 10, x = p & (Wn - 1);
            const float2* fbp = reinterpret_cast<const float2*>(flowback) + idx;
            float* o0a = reinterpret_cast<float*>(&o0);
            float* o1a = reinterpret_cast<float*>(&o1);
            float* o2a = reinterpret_cast<float*>(&o2);
#pragma unroll
            for (int k = 0; k < 4; ++k) {
                if ((nib >> k) & 1u) continue;
                float2 f = fbp[k];
                float X = (float)(x + k) + f.x;
                float Y = (float)y + f.y;
                float x0 = floorf(X), y0 = floorf(Y);
                float g0 = 0.f, g1 = 0.f, g2 = 0.f;
#pragma unroll
                for (int cy = 0; cy < 2; ++cy) {
#pragma unroll
                    for (int cx = 0; cx < 2; ++cx) {
                        float xi = x0 + (float)cx;
                        float yi = y0 + (float)cy;
                        if (xi < 0.f || xi > (float)(Wn - 1) ||
                            yi < 0.f || yi > (float)(Hn - 1)) continue;
                        float w = (1.f - fabsf(X - xi)) * (1.f - fabsf(Y - yi));
                        int gi = (int)yi * Wn + (int)xi;
                        g0 += sb[gi] * w;
                        g1 += sb[HW + gi] * w;
                        g2 += sb[2 * HW + gi] * w;
                    }
                }
                o0a[k] = g0; o1a[k] = g1; o2a[k] = g2;
            }
        }
        float* db = dst + (size_t)b * Cn * HW;
        *reinterpret_cast<float4*>(&db[p])          = o0;
        *reinterpret_cast<float4*>(&db[HW + p])     = o1;
        *reinterpret_cast<float4*>(&db[2 * HW + p]) = o2;
    }
}

// ------- if iteration count even (incl. 0), result sits in acc: copy out -----
__global__ __launch_bounds__(BLK) void copy_even_kernel(
    const float* __restrict__ A, float* __restrict__ dst,
    const int* __restrict__ n_iter)
{
    int n = *n_iter; if (n > MAX_ITERS) n = MAX_ITERS;
    if (n & 1) return;   // odd: result already in dst
    for (int q = blockIdx.x * BLK + threadIdx.x; q < BCHW / 4;
         q += gridDim.x * BLK) {
        int i = q * 4;
        *reinterpret_cast<float4*>(&dst[i]) =
            *reinterpret_cast<const float4*>(&A[i]);
    }
}

extern "C" void kernel_launch(void* const* d_in, const int* in_sizes, int n_in,
                              void* d_out, int out_size, void* d_ws, size_t ws_size,
                              hipStream_t stream)
{
    const float* im0      = (const float*)d_in[0];
    const float* flow     = (const float*)d_in[1];
    const float* flowback = (const float*)d_in[2];
    const int*   n_iter   = (const int*)d_in[3];
    float* out = (float*)d_out;
    float* acc = (float*)d_ws;                       // BCHW floats (50.3 MB)
    unsigned* wm = (unsigned*)(acc + BCHW);          // BHW/32 mask words (0.5 MB)
    unsigned* fb_count = wm + BHW / 32;              // 1 word (+pad)
    unsigned* fb_list  = fb_count + 16;              // FB_CAP words (2 MB)

    hipMemsetAsync(fb_count, 0, sizeof(unsigned), stream);

    // owner splat writes every acc element and every mask word -> no memset
    splat_owner<<<Bn * 256, 1024, 0, stream>>>(im0, flow, acc, wm,
                                               fb_count, fb_list);

    splat_fallback<<<128, BLK, 0, stream>>>(im0, flow, acc, wm,
                                            fb_count, fb_list);

    // ping-pong: iter 0: acc->out, iter 1: out->acc, ...
    // iters >=1 get small grids (grid-stride keeps them correct if n>1;
    // benchmark input has n==1 so they are gated no-ops)
    for (int i = 0; i < MAX_ITERS; ++i) {
        const float* s = (i % 2 == 0) ? acc : out;
        float*       d = (i % 2 == 0) ? out : acc;
        int g = (i == 0) ? 2048 : 264;
        infill_kernel<<<g, BLK, 0, stream>>>(s, wm, flowback, d, n_iter, i);
    }

    copy_even_kernel<<<264, BLK, 0, stream>>>(acc, out, n_iter);
}

// Round 10
// 110.163 us; speedup vs baseline: 3.8147x; 1.1006x over previous
//
#include <hip/hip_runtime.h>

#define BLK 256

constexpr int Bn = 4, Cn = 3, Hn = 1024, Wn = 1024;
constexpr int HW   = Hn * Wn;        // 1<<20
constexpr int BHW  = Bn * HW;        // 4,194,304
constexpr int BCHW = Bn * Cn * HW;   // 12,582,912
constexpr int MAX_ITERS = 4;

// dest-tile ownership splat
constexpr int TS  = 64;              // dest tile side
constexpr int Mg  = 24;              // source window margin
constexpr int WND = TS + 2 * Mg;     // 112
constexpr int NW  = WND * WND;       // 12544
constexpr float FMAX = 23.0f;        // = Mg-1; owner handles |f|<=FMAX exactly

// packed-u64 carry-free fixed point (R9 post-mortem: R7's u64 regression was
// the in-loop global atomic, NOT the u64 LDS atomic -- retest cleanly):
//   word1: hi = c1*2^13 (mod 2^32 exact), lo = c0*2^13 + 2^19 per event
//          (addend < 2^20; max 2304 events/cell * 2^20 < 2^32 -> carry-free)
//   word2: hi = c2*2^13, lo = +1/event (exact count n; n>0 == hole flag)
// Flush: n = lo2; c0 = lo1 - n*2^19 (exact); c1/c2 = (int)hi.
constexpr float SCALE = 8192.0f;                 // 2^13
constexpr float INVSC = 1.220703125e-04f;        // 2^-13 exact
constexpr int   BIAS_I = 524288;                 // 2^19

// flow-only prefetch; sentinel 1e9 fails the FMAX test for out-of-image px
#define STAGEF(PRED, WY, WX, F, PX, PY)                                       \
    {   PY = ty - Mg + (WY);                                                  \
        PX = tx - Mg + (WX);                                                  \
        F = make_float2(1e9f, 1e9f);                                          \
        if ((PRED) && (unsigned)PY < (unsigned)Hn &&                          \
            (unsigned)PX < (unsigned)Wn)                                      \
            F = flb[(PY << 10) + PX];                                         \
    }

__global__ __launch_bounds__(1024, 8) void splat_owner(
    const float* __restrict__ im0, const float* __restrict__ flow,
    float* __restrict__ acc, unsigned* __restrict__ wm)
{
    __shared__ unsigned long long s_w1[TS * TS];  // [c1 | c0+bias]  32 KiB
    __shared__ unsigned long long s_w2[TS * TS];  // [c2 | count  ]  32 KiB
    // XCD-bijective swizzle (1024 blocks, 8 XCDs): contiguous tile rows/XCD
    const int bid  = ((blockIdx.x & 7) << 7) | (blockIdx.x >> 3);
    const int b    = bid >> 8;        // 256 tiles per batch (16x16)
    const int tile = bid & 255;
    const int ty   = (tile >> 4) * TS;
    const int tx   = (tile & 15) * TS;

    for (int i = threadIdx.x; i < TS * TS; i += 1024) {
        s_w1[i] = 0ull; s_w2[i] = 0ull;
    }
    __syncthreads();

    const float*  imb = im0 + (size_t)b * Cn * HW;
    const float2* flb = reinterpret_cast<const float2*>(flow) + (size_t)b * HW;

    int i  = threadIdx.x;
    int wy = i / WND, wx = i - wy * WND;      // one-time div (i < 1024)
    int axp, ayp; float2 fA;
    STAGEF(true, wy, wx, fA, axp, ayp);

    while (i < NW) {
        int ni  = i + 1024;
        int nwx = wx + (1024 % WND);          // +16
        int nwy = wy + (1024 / WND);          // +9
        if (nwx >= WND) { nwx -= WND; ++nwy; }
        // prefetch next visit's flow before processing this one
        int bxp, byp; float2 fB;
        STAGEF(ni < NW, nwy, nwx, fB, bxp, byp);

        if (fabsf(fA.x) <= FMAX && fabsf(fA.y) <= FMAX) {
            float X = (float)axp + fA.x;
            float Y = (float)ayp + fA.y;
            float x0 = floorf(X), y0 = floorf(Y);
            int lx0 = (int)x0 - tx;
            int ly0 = (int)y0 - ty;
            // box reject: any of the 2x2 corners inside this tile?
            if (lx0 >= -1 && lx0 < TS && ly0 >= -1 && ly0 < TS) {
                // shared bilinear factors; per-corner product identical to ref
                float wxa = 1.f - fabsf(X - x0);
                float wxb = 1.f - fabsf(X - (x0 + 1.f));
                float wya = 1.f - fabsf(Y - y0);
                float wyb = 1.f - fabsf(Y - (y0 + 1.f));
                float w00 = wxa * wya, w01 = wxb * wya;
                float w10 = wxa * wyb, w11 = wxb * wyb;
                bool i00 = (unsigned)ly0     < (unsigned)TS && (unsigned)lx0     < (unsigned)TS && w00 != 0.f;
                bool i01 = (unsigned)ly0     < (unsigned)TS && (unsigned)(lx0+1) < (unsigned)TS && w01 != 0.f;
                bool i10 = (unsigned)(ly0+1) < (unsigned)TS && (unsigned)lx0     < (unsigned)TS && w10 != 0.f;
                bool i11 = (unsigned)(ly0+1) < (unsigned)TS && (unsigned)(lx0+1) < (unsigned)TS && w11 != 0.f;
                if (i00 | i01 | i10 | i11) {
                    // im0 loads only when this pixel actually contributes
                    int p_ = (ayp << 10) + axp;
                    float sv0 = imb[p_]          * SCALE;
                    float sv1 = imb[HW + p_]     * SCALE;
                    float sv2 = imb[2 * HW + p_] * SCALE;
#define CORNER(II, C, W)                                                       \
    if (II) {                                                                  \
        int c_ = (C);                                                          \
        unsigned long long a1 =                                                \
            ((unsigned long long)(unsigned)__float2int_rz(sv1 * (W)) << 32) |  \
            (unsigned long long)(unsigned)(__float2int_rz(sv0 * (W)) + BIAS_I);\
        unsigned long long a2 =                                                \
            ((unsigned long long)(unsigned)__float2int_rz(sv2 * (W)) << 32) |  \
            1ull;                                                              \
        atomicAdd(&s_w1[c_], a1);                                              \
        atomicAdd(&s_w2[c_], a2);                                              \
    }
                    CORNER(i00, ly0 * TS + lx0,           w00)
                    CORNER(i01, ly0 * TS + lx0 + 1,       w01)
                    CORNER(i10, (ly0 + 1) * TS + lx0,     w10)
                    CORNER(i11, (ly0 + 1) * TS + lx0 + 1, w11)
#undef CORNER
                }
            }
        }
        i = ni; wy = nwy; wx = nwx;
        fA = fB; axp = bxp; ayp = byp;
    }
    __syncthreads();

    float* accb = acc + (size_t)b * Cn * HW;
    const int lane = threadIdx.x & 63;
    for (int i2 = threadIdx.x; i2 < TS * TS; i2 += 1024) {
        unsigned long long w1 = s_w1[i2], w2 = s_w2[i2];
        unsigned n  = (unsigned)w2;                       // exact event count
        int c0 = (int)((unsigned)w1 - (n << 19));         // exact bias removal
        int c1 = (int)(unsigned)(w1 >> 32);
        int c2 = (int)(unsigned)(w2 >> 32);
        int row = i2 >> 6;                    // wave <-> one 64-px tile row
        int p = ((ty + row) << 10) + tx + (i2 & 63);
        accb[p]          = (float)c0 * INVSC;
        accb[HW + p]     = (float)c1 * INVSC;
        accb[2 * HW + p] = (float)c2 * INVSC;
        unsigned long long m = __ballot(n != 0);
        int wbase = (b * HW + ((ty + row) << 10) + tx) >> 5;
        if (lane == 0)  wm[wbase]     = (unsigned)m;
        if (lane == 32) wm[wbase + 1] = (unsigned)(m >> 32);
    }
}

// ------- fallback: the rare |flow|>FMAX pixels, scattered atomics -------
// full rescan (R6-style; R9's list machinery was net-negative). Runs AFTER
// owner flush; planes are float by then; mask-bit OR preserves !=0 semantics.
__global__ __launch_bounds__(BLK) void splat_fallback(
    const float* __restrict__ im0, const float* __restrict__ flow,
    float* __restrict__ acc, unsigned* __restrict__ wm)
{
    int t = blockIdx.x * BLK + threadIdx.x;
    if (t >= BHW / 2) return;
    int idx0 = t * 2;
    float4 ff = *reinterpret_cast<const float4*>(&flow[(size_t)idx0 * 2]);

#pragma unroll
    for (int k = 0; k < 2; ++k) {
        float fx = k ? ff.z : ff.x;
        float fy = k ? ff.w : ff.y;
        if (fabsf(fx) <= FMAX && fabsf(fy) <= FMAX) continue;  // owner handled
        int idx = idx0 + k;
        int b = idx >> 20;
        int p = idx & (HW - 1);
        int y = p >> 10;
        int x = p & (Wn - 1);
        float X = (float)x + fx;
        float Y = (float)y + fy;
        float x0 = floorf(X), y0 = floorf(Y);
        float v0 = im0[(b * Cn + 0) * HW + p];
        float v1 = im0[(b * Cn + 1) * HW + p];
        float v2 = im0[(b * Cn + 2) * HW + p];
#pragma unroll
        for (int cy = 0; cy < 2; ++cy) {
#pragma unroll
            for (int cx = 0; cx < 2; ++cx) {
                float xi = x0 + (float)cx;
                float yi = y0 + (float)cy;
                if (xi < 0.f || xi > (float)(Wn - 1) ||
                    yi < 0.f || yi > (float)(Hn - 1)) continue;
                float w = (1.f - fabsf(X - xi)) * (1.f - fabsf(Y - yi));
                if (w == 0.f) continue;
                int di = (int)yi * Wn + (int)xi;
                int gi = b * HW + di;
                atomicOr(&wm[gi >> 5], 1u << (gi & 31));
                atomicAdd(&acc[(b * Cn + 0) * HW + di], v0 * w);
                atomicAdd(&acc[(b * Cn + 1) * HW + di], v1 * w);
                atomicAdd(&acc[(b * Cn + 2) * HW + di], v2 * w);
            }
        }
    }
}

// ------- infill iteration: dst = where(hole, gather(src,flowback), src) -----
// 4 px/thread float4, grid-stride; gather only at holes (~2-3%).
__global__ __launch_bounds__(BLK) void infill_kernel(
    const float* __restrict__ src, const unsigned* __restrict__ wm,
    const float* __restrict__ flowback, float* __restrict__ dst,
    const int* __restrict__ n_iter, int iter)
{
    int n = *n_iter; if (n > MAX_ITERS) n = MAX_ITERS;
    if (iter >= n) return;

    for (int q = blockIdx.x * BLK + threadIdx.x; q < BHW / 4;
         q += gridDim.x * BLK) {
        int idx = q * 4;
        int b = idx >> 20;
        int p = idx & (HW - 1);

        const float* sb = src + (size_t)b * Cn * HW;
        unsigned nib = (wm[idx >> 5] >> (idx & 31)) & 0xFu;
        float4 o0 = *reinterpret_cast<const float4*>(&sb[p]);
        float4 o1 = *reinterpret_cast<const float4*>(&sb[HW + p]);
        float4 o2 = *reinterpret_cast<const float4*>(&sb[2 * HW + p]);

        if (nib != 0xFu) {
            int y = p >> 10, x = p & (Wn - 1);
            const float2* fbp = reinterpret_cast<const float2*>(flowback) + idx;
            float* o0a = reinterpret_cast<float*>(&o0);
            float* o1a = reinterpret_cast<float*>(&o1);
            float* o2a = reinterpret_cast<float*>(&o2);
#pragma unroll
            for (int k = 0; k < 4; ++k) {
                if ((nib >> k) & 1u) continue;
                float2 f = fbp[k];
                float X = (float)(x + k) + f.x;
                float Y = (float)y + f.y;
                float x0 = floorf(X), y0 = floorf(Y);
                float g0 = 0.f, g1 = 0.f, g2 = 0.f;
#pragma unroll
                for (int cy = 0; cy < 2; ++cy) {
#pragma unroll
                    for (int cx = 0; cx < 2; ++cx) {
                        float xi = x0 + (float)cx;
                        float yi = y0 + (float)cy;
                        if (xi < 0.f || xi > (float)(Wn - 1) ||
                            yi < 0.f || yi > (float)(Hn - 1)) continue;
                        float w = (1.f - fabsf(X - xi)) * (1.f - fabsf(Y - yi));
                        int gi = (int)yi * Wn + (int)xi;
                        g0 += sb[gi] * w;
                        g1 += sb[HW + gi] * w;
                        g2 += sb[2 * HW + gi] * w;
                    }
                }
                o0a[k] = g0; o1a[k] = g1; o2a[k] = g2;
            }
        }
        float* db = dst + (size_t)b * Cn * HW;
        *reinterpret_cast<float4*>(&db[p])          = o0;
        *reinterpret_cast<float4*>(&db[HW + p])     = o1;
        *reinterpret_cast<float4*>(&db[2 * HW + p]) = o2;
    }
}

// ------- if iteration count even (incl. 0), result sits in acc: copy out -----
__global__ __launch_bounds__(BLK) void copy_even_kernel(
    const float* __restrict__ A, float* __restrict__ dst,
    const int* __restrict__ n_iter)
{
    int n = *n_iter; if (n > MAX_ITERS) n = MAX_ITERS;
    if (n & 1) return;   // odd: result already in dst
    for (int q = blockIdx.x * BLK + threadIdx.x; q < BCHW / 4;
         q += gridDim.x * BLK) {
        int i = q * 4;
        *reinterpret_cast<float4*>(&dst[i]) =
            *reinterpret_cast<const float4*>(&A[i]);
    }
}

extern "C" void kernel_launch(void* const* d_in, const int* in_sizes, int n_in,
                              void* d_out, int out_size, void* d_ws, size_t ws_size,
                              hipStream_t stream)
{
    const float* im0      = (const float*)d_in[0];
    const float* flow     = (const float*)d_in[1];
    const float* flowback = (const float*)d_in[2];
    const int*   n_iter   = (const int*)d_in[3];
    float* out = (float*)d_out;
    float* acc = (float*)d_ws;                       // BCHW floats (50.3 MB)
    unsigned* wm = (unsigned*)(acc + BCHW);          // BHW/32 mask words (0.5 MB)

    // owner splat writes every acc element and every mask word -> no memset
    splat_owner<<<Bn * 256, 1024, 0, stream>>>(im0, flow, acc, wm);

    splat_fallback<<<(BHW / 2) / BLK, BLK, 0, stream>>>(im0, flow, acc, wm);

    // ping-pong: iter 0: acc->out, iter 1: out->acc, ...
    // iters >=1 get small grids (grid-stride keeps them correct if n>1;
    // benchmark input has n==1 so they are gated no-ops)
    for (int i = 0; i < MAX_ITERS; ++i) {
        const float* s = (i % 2 == 0) ? acc : out;
        float*       d = (i % 2 == 0) ? out : acc;
        int g = (i == 0) ? 2048 : 264;
        infill_kernel<<<g, BLK, 0, stream>>>(s, wm, flowback, d, n_iter, i);
    }

    copy_even_kernel<<<264, BLK, 0, stream>>>(acc, out, n_iter);
}

// Round 11
// 108.159 us; speedup vs baseline: 3.8854x; 1.0185x over previous
//
#include <hip/hip_runtime.h>

#define BLK 256

constexpr int Bn = 4, Cn = 3, Hn = 1024, Wn = 1024;
constexpr int HW   = Hn * Wn;        // 1<<20
constexpr int BHW  = Bn * HW;        // 4,194,304
constexpr int BCHW = Bn * Cn * HW;   // 12,582,912
constexpr int MAX_ITERS = 4;

// dest-tile ownership splat
constexpr int TS  = 64;              // dest tile side
constexpr int Mg  = 24;              // source window margin
constexpr int WND = TS + 2 * Mg;     // 112
constexpr int NPAIR = WND * WND / 2; // 6272 horizontal pixel-pairs
constexpr int PPR = WND / 2;         // 56 pairs per row
constexpr float FMAX = 23.0f;        // = Mg-1; owner handles |f|<=FMAX exactly

// packed-u64 carry-free fixed point (R10: u64 LDS atomics native-fast):
//   word1: hi = c1*2^13 (mod 2^32 exact), lo = c0*2^13 + 2^19 per event
//   word2: hi = c2*2^13, lo = +1/event (exact count n; n>0 == hole flag)
constexpr float SCALE = 8192.0f;                 // 2^13
constexpr float INVSC = 1.220703125e-04f;        // 2^-13 exact
constexpr int   BIAS_I = 524288;                 // 2^19

// pair flow prefetch: 2 adjacent px, one float4 load (16B). x even =>
// pair is all-or-nothing valid: (unsigned)x < Wn-1. Sentinel 1e9 fails FMAX.
#define STAGEP(PRED, WY, WP, F4, PX, PY)                                      \
    {   PY = ty - Mg + (WY);                                                  \
        PX = tx - Mg + ((WP) << 1);                                           \
        F4 = make_float4(1e9f, 1e9f, 1e9f, 1e9f);                             \
        if ((PRED) && (unsigned)PY < (unsigned)Hn &&                          \
            (unsigned)PX < (unsigned)(Wn - 1))                                \
            F4 = *reinterpret_cast<const float4*>(&flb[(PY << 10) + PX]);     \
    }

__global__ __launch_bounds__(1024, 8) void splat_owner(
    const float* __restrict__ im0, const float* __restrict__ flow,
    float* __restrict__ acc, unsigned* __restrict__ wm)
{
    __shared__ unsigned long long s_w1[TS * TS];  // [c1 | c0+bias]  32 KiB
    __shared__ unsigned long long s_w2[TS * TS];  // [c2 | count  ]  32 KiB
    // XCD-bijective swizzle (1024 blocks, 8 XCDs): contiguous tile rows/XCD
    const int bid  = ((blockIdx.x & 7) << 7) | (blockIdx.x >> 3);
    const int b    = bid >> 8;        // 256 tiles per batch (16x16)
    const int tile = bid & 255;
    const int ty   = (tile >> 4) * TS;
    const int tx   = (tile & 15) * TS;

    for (int i = threadIdx.x; i < TS * TS; i += 1024) {
        s_w1[i] = 0ull; s_w2[i] = 0ull;
    }
    __syncthreads();

    const float*  imb = im0 + (size_t)b * Cn * HW;
    const float2* flb = reinterpret_cast<const float2*>(flow) + (size_t)b * HW;

    int t  = threadIdx.x;
    int wy = t / PPR, wp = t - wy * PPR;      // one-time div (t < 1024)
    int axp, ayp; float4 fA;
    STAGEP(true, wy, wp, fA, axp, ayp);

    while (t < NPAIR) {
        int nt  = t + 1024;
        int nwp = wp + (1024 % PPR);          // +16
        int nwy = wy + (1024 / PPR);          // +18
        if (nwp >= PPR) { nwp -= PPR; ++nwy; }
        // prefetch next pair's flow before processing this one
        int bxp, byp; float4 fB;
        STAGEP(nt < NPAIR, nwy, nwp, fB, bxp, byp);

#pragma unroll
        for (int k = 0; k < 2; ++k) {
            float fx = k ? fA.z : fA.x;
            float fy = k ? fA.w : fA.y;
            if (!(fabsf(fx) <= FMAX && fabsf(fy) <= FMAX)) continue;
            float X = (float)(axp + k) + fx;
            float Y = (float)ayp + fy;
            float x0 = floorf(X), y0 = floorf(Y);
            int lx0 = (int)x0 - tx;
            int ly0 = (int)y0 - ty;
            // box reject: any of the 2x2 corners inside this tile?
            if (!(lx0 >= -1 && lx0 < TS && ly0 >= -1 && ly0 < TS)) continue;
            // shared bilinear factors; per-corner product identical to ref
            float wxa = 1.f - fabsf(X - x0);
            float wxb = 1.f - fabsf(X - (x0 + 1.f));
            float wya = 1.f - fabsf(Y - y0);
            float wyb = 1.f - fabsf(Y - (y0 + 1.f));
            float w00 = wxa * wya, w01 = wxb * wya;
            float w10 = wxa * wyb, w11 = wxb * wyb;
            bool i00 = (unsigned)ly0     < (unsigned)TS && (unsigned)lx0     < (unsigned)TS && w00 != 0.f;
            bool i01 = (unsigned)ly0     < (unsigned)TS && (unsigned)(lx0+1) < (unsigned)TS && w01 != 0.f;
            bool i10 = (unsigned)(ly0+1) < (unsigned)TS && (unsigned)lx0     < (unsigned)TS && w10 != 0.f;
            bool i11 = (unsigned)(ly0+1) < (unsigned)TS && (unsigned)(lx0+1) < (unsigned)TS && w11 != 0.f;
            if (!(i00 | i01 | i10 | i11)) continue;
            // im0 loads only when this pixel actually contributes
            int p_ = (ayp << 10) + axp + k;
            float sv0 = imb[p_]          * SCALE;
            float sv1 = imb[HW + p_]     * SCALE;
            float sv2 = imb[2 * HW + p_] * SCALE;
#define CORNER(II, C, W)                                                       \
    if (II) {                                                                  \
        int c_ = (C);                                                          \
        unsigned long long a1 =                                                \
            ((unsigned long long)(unsigned)__float2int_rz(sv1 * (W)) << 32) |  \
            (unsigned long long)(unsigned)(__float2int_rz(sv0 * (W)) + BIAS_I);\
        unsigned long long a2 =                                                \
            ((unsigned long long)(unsigned)__float2int_rz(sv2 * (W)) << 32) |  \
            1ull;                                                              \
        atomicAdd(&s_w1[c_], a1);                                              \
        atomicAdd(&s_w2[c_], a2);                                              \
    }
            CORNER(i00, ly0 * TS + lx0,           w00)
            CORNER(i01, ly0 * TS + lx0 + 1,       w01)
            CORNER(i10, (ly0 + 1) * TS + lx0,     w10)
            CORNER(i11, (ly0 + 1) * TS + lx0 + 1, w11)
#undef CORNER
        }
        t = nt; wy = nwy; wp = nwp;
        fA = fB; axp = bxp; ayp = byp;
    }
    __syncthreads();

    float* accb = acc + (size_t)b * Cn * HW;
    const int lane = threadIdx.x & 63;
    for (int i2 = threadIdx.x; i2 < TS * TS; i2 += 1024) {
        unsigned long long w1 = s_w1[i2], w2 = s_w2[i2];
        unsigned n  = (unsigned)w2;                       // exact event count
        int c0 = (int)((unsigned)w1 - (n << 19));         // exact bias removal
        int c1 = (int)(unsigned)(w1 >> 32);
        int c2 = (int)(unsigned)(w2 >> 32);
        int row = i2 >> 6;                    // wave <-> one 64-px tile row
        int p = ((ty + row) << 10) + tx + (i2 & 63);
        accb[p]          = (float)c0 * INVSC;
        accb[HW + p]     = (float)c1 * INVSC;
        accb[2 * HW + p] = (float)c2 * INVSC;
        unsigned long long m = __ballot(n != 0);
        int wbase = (b * HW + ((ty + row) << 10) + tx) >> 5;
        if (lane == 0)  wm[wbase]     = (unsigned)m;
        if (lane == 32) wm[wbase + 1] = (unsigned)(m >> 32);
    }
}

// ------- fallback: the rare |flow|>FMAX pixels, scattered atomics -------
// full rescan (R9's list machinery was net-negative). Runs AFTER owner
// flush; planes are float by then; mask-bit OR preserves !=0 semantics.
__global__ __launch_bounds__(BLK) void splat_fallback(
    const float* __restrict__ im0, const float* __restrict__ flow,
    float* __restrict__ acc, unsigned* __restrict__ wm)
{
    int t = blockIdx.x * BLK + threadIdx.x;
    if (t >= BHW / 2) return;
    int idx0 = t * 2;
    float4 ff = *reinterpret_cast<const float4*>(&flow[(size_t)idx0 * 2]);

#pragma unroll
    for (int k = 0; k < 2; ++k) {
        float fx = k ? ff.z : ff.x;
        float fy = k ? ff.w : ff.y;
        if (fabsf(fx) <= FMAX && fabsf(fy) <= FMAX) continue;  // owner handled
        int idx = idx0 + k;
        int b = idx >> 20;
        int p = idx & (HW - 1);
        int y = p >> 10;
        int x = p & (Wn - 1);
        float X = (float)x + fx;
        float Y = (float)y + fy;
        float x0 = floorf(X), y0 = floorf(Y);
        float v0 = im0[(b * Cn + 0) * HW + p];
        float v1 = im0[(b * Cn + 1) * HW + p];
        float v2 = im0[(b * Cn + 2) * HW + p];
#pragma unroll
        for (int cy = 0; cy < 2; ++cy) {
#pragma unroll
            for (int cx = 0; cx < 2; ++cx) {
                float xi = x0 + (float)cx;
                float yi = y0 + (float)cy;
                if (xi < 0.f || xi > (float)(Wn - 1) ||
                    yi < 0.f || yi > (float)(Hn - 1)) continue;
                float w = (1.f - fabsf(X - xi)) * (1.f - fabsf(Y - yi));
                if (w == 0.f) continue;
                int di = (int)yi * Wn + (int)xi;
                int gi = b * HW + di;
                atomicOr(&wm[gi >> 5], 1u << (gi & 31));
                atomicAdd(&acc[(b * Cn + 0) * HW + di], v0 * w);
                atomicAdd(&acc[(b * Cn + 1) * HW + di], v1 * w);
                atomicAdd(&acc[(b * Cn + 2) * HW + di], v2 * w);
            }
        }
    }
}

// ------- infill iteration: dst = where(hole, gather(src,flowback), src) -----
// 4 px/thread float4, grid-stride; gather only at holes (~2-3%).
__global__ __launch_bounds__(BLK) void infill_kernel(
    const float* __restrict__ src, const unsigned* __restrict__ wm,
    const float* __restrict__ flowback, float* __restrict__ dst,
    const int* __restrict__ n_iter, int iter)
{
    int n = *n_iter; if (n > MAX_ITERS) n = MAX_ITERS;
    if (iter >= n) return;

    for (int q = blockIdx.x * BLK + threadIdx.x; q < BHW / 4;
         q += gridDim.x * BLK) {
        int idx = q * 4;
        int b = idx >> 20;
        int p = idx & (HW - 1);

        const float* sb = src + (size_t)b * Cn * HW;
        unsigned nib = (wm[idx >> 5] >> (idx & 31)) & 0xFu;
        float4 o0 = *reinterpret_cast<const float4*>(&sb[p]);
        float4 o1 = *reinterpret_cast<const float4*>(&sb[HW + p]);
        float4 o2 = *reinterpret_cast<const float4*>(&sb[2 * HW + p]);

        if (nib != 0xFu) {
            int y = p >> 10, x = p & (Wn - 1);
            const float2* fbp = reinterpret_cast<const float2*>(flowback) + idx;
            float* o0a = reinterpret_cast<float*>(&o0);
            float* o1a = reinterpret_cast<float*>(&o1);
            float* o2a = reinterpret_cast<float*>(&o2);
#pragma unroll
            for (int k = 0; k < 4; ++k) {
                if ((nib >> k) & 1u) continue;
                float2 f = fbp[k];
                float X = (float)(x + k) + f.x;
                float Y = (float)y + f.y;
                float x0 = floorf(X), y0 = floorf(Y);
                float g0 = 0.f, g1 = 0.f, g2 = 0.f;
#pragma unroll
                for (int cy = 0; cy < 2; ++cy) {
#pragma unroll
                    for (int cx = 0; cx < 2; ++cx) {
                        float xi = x0 + (float)cx;
                        float yi = y0 + (float)cy;
                        if (xi < 0.f || xi > (float)(Wn - 1) ||
                            yi < 0.f || yi > (float)(Hn - 1)) continue;
                        float w = (1.f - fabsf(X - xi)) * (1.f - fabsf(Y - yi));
                        int gi = (int)yi * Wn + (int)xi;
                        g0 += sb[gi] * w;
                        g1 += sb[HW + gi] * w;
                        g2 += sb[2 * HW + gi] * w;
                    }
                }
                o0a[k] = g0; o1a[k] = g1; o2a[k] = g2;
            }
        }
        float* db = dst + (size_t)b * Cn * HW;
        *reinterpret_cast<float4*>(&db[p])          = o0;
        *reinterpret_cast<float4*>(&db[HW + p])     = o1;
        *reinterpret_cast<float4*>(&db[2 * HW + p]) = o2;
    }
}

// ------- if iteration count even (incl. 0), result sits in acc: copy out -----
__global__ __launch_bounds__(BLK) void copy_even_kernel(
    const float* __restrict__ A, float* __restrict__ dst,
    const int* __restrict__ n_iter)
{
    int n = *n_iter; if (n > MAX_ITERS) n = MAX_ITERS;
    if (n & 1) return;   // odd: result already in dst
    for (int q = blockIdx.x * BLK + threadIdx.x; q < BCHW / 4;
         q += gridDim.x * BLK) {
        int i = q * 4;
        *reinterpret_cast<float4*>(&dst[i]) =
            *reinterpret_cast<const float4*>(&A[i]);
    }
}

extern "C" void kernel_launch(void* const* d_in, const int* in_sizes, int n_in,
                              void* d_out, int out_size, void* d_ws, size_t ws_size,
                              hipStream_t stream)
{
    const float* im0      = (const float*)d_in[0];
    const float* flow     = (const float*)d_in[1];
    const float* flowback = (const float*)d_in[2];
    const int*   n_iter   = (const int*)d_in[3];
    float* out = (float*)d_out;
    float* acc = (float*)d_ws;                       // BCHW floats (50.3 MB)
    unsigned* wm = (unsigned*)(acc + BCHW);          // BHW/32 mask words (0.5 MB)

    // owner splat writes every acc element and every mask word -> no memset
    splat_owner<<<Bn * 256, 1024, 0, stream>>>(im0, flow, acc, wm);

    splat_fallback<<<(BHW / 2) / BLK, BLK, 0, stream>>>(im0, flow, acc, wm);

    // ping-pong: iter 0: acc->out, iter 1: out->acc, ...
    // iters >=1 get small grids (grid-stride keeps them correct if n>1;
    // benchmark input has n==1 so they are gated no-ops)
    for (int i = 0; i < MAX_ITERS; ++i) {
        const float* s = (i % 2 == 0) ? acc : out;
        float*       d = (i % 2 == 0) ? out : acc;
        int g = (i == 0) ? 4096 : 264;
        infill_kernel<<<g, BLK, 0, stream>>>(s, wm, flowback, d, n_iter, i);
    }

    copy_even_kernel<<<264, BLK, 0, stream>>>(acc, out, n_iter);
}